// Round 1
// baseline (544.567 us; speedup 1.0000x reference)
//
#include <hip/hip_runtime.h>
#include <stdint.h>

// ---------------------------------------------------------------------------
// UpBlock: 5 chained sparse convs (gather-GEMM), bf16 MFMA, occupancy-first.
// out[i] = sum_k feats[nbr[k,i]] @ W[k]; BN+LeakyReLU epilogues; skip add L2.
//
// v2 vs v1 (536 us): v1 ran 1563 single-wave workgroups = 6.1 waves/CU (15%
// occupancy) and was latency-bound (MfmaUtil 11.5%, VALUBusy 3.5%, HBM 25%).
// v2: 32 rows/wave + K split across 2 waves/wg -> 6250 waves (16/CU VGPR cap),
// 2-deep nbr-index prefetch + 1-deep A-gather double buffer (CIN=64), LDS
// partial-sum reduce, coalesced epilogue.
//
// mfma_f32_32x32x16_bf16:
//   A[m=lane&31][k=(lane>>5)*8+j], B[k=(lane>>5)*8+j][n=lane&31]
//   C/D: col=lane&31, row=(reg&3)+8*(reg>>2)+4*(lane>>5)
// ---------------------------------------------------------------------------

typedef __bf16 bf16x8 __attribute__((ext_vector_type(8)));
typedef float f32x16 __attribute__((ext_vector_type(16)));

__device__ __forceinline__ uint16_t f2bf(float f) {
    uint32_t u = __builtin_bit_cast(uint32_t, f);
    u = (u + 0x7fffu + ((u >> 16) & 1u)) >> 16;   // round-to-nearest-even
    return (uint16_t)u;
}

__device__ __forceinline__ bf16x8 ldb8(const uint16_t* p) {
    return __builtin_bit_cast(bf16x8, *reinterpret_cast<const uint4*>(p));
}

// --- convert x_feats (f32) -> bf16, 8 elems/thread --------------------------
__global__ void convert_x(const float* __restrict__ in, uint16_t* __restrict__ out, int n8) {
    int t = blockIdx.x * blockDim.x + threadIdx.x;
    if (t >= n8) return;
    const float4* p = reinterpret_cast<const float4*>(in) + 2 * (size_t)t;
    float4 f0 = p[0], f1 = p[1];
    uint32_t w0 = (uint32_t)f2bf(f0.x) | ((uint32_t)f2bf(f0.y) << 16);
    uint32_t w1 = (uint32_t)f2bf(f0.z) | ((uint32_t)f2bf(f0.w) << 16);
    uint32_t w2 = (uint32_t)f2bf(f1.x) | ((uint32_t)f2bf(f1.y) << 16);
    uint32_t w3 = (uint32_t)f2bf(f1.z) | ((uint32_t)f2bf(f1.w) << 16);
    uint4 v; v.x = w0; v.y = w1; v.z = w2; v.w = w3;
    *reinterpret_cast<uint4*>(out + 8 * (size_t)t) = v;
}

// --- pack weights into MFMA B-fragment order + BN scale/shift ---------------
// dst element [(((k*S + s)*2 + nt)*64 + lane)*8 + j] = bf16(W[k][ci][c])
//   ci = s*16 + (lane>>5)*8 + j,  c = nt*32 + (lane&31),  S = CIN/16
__global__ void pack_weights(const float* __restrict__ w1, const float* __restrict__ wt,
                             const float* __restrict__ w2, const float* __restrict__ w3,
                             const float* __restrict__ w4, const float* __restrict__ bn,
                             uint16_t* __restrict__ p1, uint16_t* __restrict__ pt,
                             uint16_t* __restrict__ p2, uint16_t* __restrict__ p3,
                             uint16_t* __restrict__ p4, float* __restrict__ bnps) {
    int w = blockIdx.y;
    int t = blockIdx.x * blockDim.x + threadIdx.x;
    if (w == 5) {  // BN scale/shift precompute: bnps[l][0][c]=scale, [l][1][c]=shift
        if (t < 256) {
            int l = t >> 6, c = t & 63;
            float g = bn[(l * 4 + 0) * 64 + c];
            float b = bn[(l * 4 + 1) * 64 + c];
            float m = bn[(l * 4 + 2) * 64 + c];
            float v = bn[(l * 4 + 3) * 64 + c];
            float sc = g * rsqrtf(v + 1e-5f);
            bnps[(l * 2 + 0) * 64 + c] = sc;
            bnps[(l * 2 + 1) * 64 + c] = b - m * sc;
        }
        return;
    }
    const float* src; uint16_t* dst; int K, CIN;
    switch (w) {
        case 0:  src = w1; dst = p1; K = 27; CIN = 128; break;
        case 1:  src = wt; dst = pt; K = 27; CIN = 64;  break;
        case 2:  src = w2; dst = p2; K = 9;  CIN = 64;  break;
        case 3:  src = w3; dst = p3; K = 9;  CIN = 64;  break;
        default: src = w4; dst = p4; K = 27; CIN = 64;  break;
    }
    int S = CIN / 16;
    int F = K * S * 2 * 64;
    if (t >= F) return;
    int lane = t & 63;
    int r = t >> 6;
    int nt = r & 1; r >>= 1;
    int s = r % S;
    int k = r / S;
    int c = nt * 32 + (lane & 31);
    int cib = s * 16 + (lane >> 5) * 8;
    #pragma unroll
    for (int j = 0; j < 8; ++j)
        dst[(size_t)t * 8 + j] = f2bf(src[((size_t)k * CIN + cib + j) * 64 + c]);
}

// --- one sparse-conv layer ---------------------------------------------------
// 2 waves per workgroup; wave w computes taps [w?K/2:0, w?K:K/2) for the same
// 32 output rows; partials reduced through LDS; all 128 threads do the
// epilogue (16 contiguous cols each -> coalesced stores).
// MODE 0: BN+LeakyReLU -> bf16   MODE 1: +skip -> bf16   MODE 2: BN+LeakyReLU -> f32
template <int CIN, int K, int MODE>
__global__ __launch_bounds__(128, 4)
void conv_layer(const uint16_t* __restrict__ feats,  // [N][CIN] bf16
                const uint16_t* __restrict__ wf,     // packed [K][CIN/16][2][64][8] bf16
                const int* __restrict__ nbr,         // [K][N]
                const int npts,
                const float* __restrict__ bnp,       // [2][64] scale/shift (or null)
                const float* __restrict__ skip,      // [N][64] f32 (or null)
                uint16_t* __restrict__ outb,
                float* __restrict__ outf) {
    constexpr int S = CIN / 16;
    constexpr int KH = K / 2;
    constexpr bool PREF = (CIN == 64);   // A double-buffer only when regs allow
    constexpr int RS = 68;               // padded LDS row stride (floats)
    __shared__ float red[2 * 32 * RS];

    const int tid  = threadIdx.x;
    const int wave = tid >> 6;
    const int lane = tid & 63;
    const int l31  = lane & 31;
    const int hi   = lane >> 5;          // which K-half of the fragment
    const int base = blockIdx.x * 32;    // this wg's 32 output rows
    const int g0   = min(base + l31, npts - 1);

    const int k0  = wave ? KH : 0;
    const int cnt = wave ? (K - KH) : KH;

    const int* nb = nbr + (size_t)k0 * npts + g0;
    const uint16_t* wb = wf + (size_t)k0 * (S * 1024) + lane * 8;

    f32x16 acc0 = {0,0,0,0,0,0,0,0,0,0,0,0,0,0,0,0};
    f32x16 acc1 = {0,0,0,0,0,0,0,0,0,0,0,0,0,0,0,0};

    // indices prefetched 2 iterations ahead (nbr is cold-streamed from HBM)
    int ic = __builtin_nontemporal_load(nb);
    int i1 = (cnt > 1) ? __builtin_nontemporal_load(nb + (size_t)npts) : 0;

    if constexpr (PREF) {
        bf16x8 ac[S], an[S];
        {
            const uint16_t* ap = feats + (size_t)ic * CIN + hi * 8;
            #pragma unroll
            for (int s = 0; s < S; ++s) ac[s] = ldb8(ap + s * 16);
        }
        for (int kk = 0; kk < cnt; ++kk) {
            const int i2 = (kk + 2 < cnt)
                ? __builtin_nontemporal_load(nb + (size_t)(kk + 2) * npts) : 0;
            if (kk + 1 < cnt) {
                const uint16_t* ap = feats + (size_t)i1 * CIN + hi * 8;
                #pragma unroll
                for (int s = 0; s < S; ++s) an[s] = ldb8(ap + s * 16);
            }
            const uint16_t* bp = wb + (size_t)kk * (S * 1024);
            #pragma unroll
            for (int s = 0; s < S; ++s) {
                bf16x8 b0 = ldb8(bp + s * 1024);
                bf16x8 b1 = ldb8(bp + s * 1024 + 512);
                acc0 = __builtin_amdgcn_mfma_f32_32x32x16_bf16(ac[s], b0, acc0, 0, 0, 0);
                acc1 = __builtin_amdgcn_mfma_f32_32x32x16_bf16(ac[s], b1, acc1, 0, 0, 0);
            }
            if (kk + 1 < cnt) {
                #pragma unroll
                for (int s = 0; s < S; ++s) ac[s] = an[s];
            }
            i1 = i2;
        }
    } else {
        for (int kk = 0; kk < cnt; ++kk) {
            const int i2 = (kk + 2 < cnt)
                ? __builtin_nontemporal_load(nb + (size_t)(kk + 2) * npts) : 0;
            const uint16_t* ap = feats + (size_t)ic * CIN + hi * 8;
            bf16x8 ac[S];
            #pragma unroll
            for (int s = 0; s < S; ++s) ac[s] = ldb8(ap + s * 16);
            const uint16_t* bp = wb + (size_t)kk * (S * 1024);
            #pragma unroll
            for (int s = 0; s < S; ++s) {
                bf16x8 b0 = ldb8(bp + s * 1024);
                bf16x8 b1 = ldb8(bp + s * 1024 + 512);
                acc0 = __builtin_amdgcn_mfma_f32_32x32x16_bf16(ac[s], b0, acc0, 0, 0, 0);
                acc1 = __builtin_amdgcn_mfma_f32_32x32x16_bf16(ac[s], b1, acc1, 0, 0, 0);
            }
            ic = i1; i1 = i2;
        }
    }

    // --- partial-sum reduce through LDS (conflict-free: bank = (4*row+l31)%32)
    #pragma unroll
    for (int reg = 0; reg < 16; ++reg) {
        const int row = (reg & 3) + 8 * (reg >> 2) + 4 * hi;
        red[wave * (32 * RS) + row * RS + l31]      = acc0[reg];
        red[wave * (32 * RS) + row * RS + 32 + l31] = acc1[reg];
    }
    __syncthreads();

    // --- epilogue: thread t -> row t>>2, cols 16*(t&3)..+15 (coalesced) -----
    const int er = tid >> 2;
    const int ec = (tid & 3) * 16;
    const int grow = base + er;
    if (grow >= npts) return;

    float v[16];
    #pragma unroll
    for (int j = 0; j < 16; ++j)
        v[j] = red[er * RS + ec + j] + red[32 * RS + er * RS + ec + j];

    if constexpr (MODE == 1) {
        const float* sp = skip + (size_t)grow * 64 + ec;
        #pragma unroll
        for (int j = 0; j < 16; ++j) v[j] += sp[j];
    } else {
        #pragma unroll
        for (int j = 0; j < 16; ++j) {
            float y = v[j] * bnp[ec + j] + bnp[64 + ec + j];
            v[j] = y >= 0.f ? y : 0.01f * y;
        }
    }

    if constexpr (MODE == 2) {
        float4* op = reinterpret_cast<float4*>(outf + (size_t)grow * 64 + ec);
        #pragma unroll
        for (int q = 0; q < 4; ++q)
            op[q] = make_float4(v[4*q+0], v[4*q+1], v[4*q+2], v[4*q+3]);
    } else {
        uint32_t w[8];
        #pragma unroll
        for (int q = 0; q < 8; ++q)
            w[q] = (uint32_t)f2bf(v[2*q]) | ((uint32_t)f2bf(v[2*q+1]) << 16);
        uint4* op = reinterpret_cast<uint4*>(outb + (size_t)grow * 64 + ec);
        op[0] = make_uint4(w[0], w[1], w[2], w[3]);
        op[1] = make_uint4(w[4], w[5], w[6], w[7]);
    }
}

extern "C" void kernel_launch(void* const* d_in, const int* in_sizes, int n_in,
                              void* d_out, int out_size, void* d_ws, size_t ws_size,
                              hipStream_t stream) {
    const int N = in_sizes[0] / 128;
    const float* x    = (const float*)d_in[0];
    const float* skip = (const float*)d_in[1];
    const float* W1   = (const float*)d_in[2];
    const float* Wt   = (const float*)d_in[3];
    const float* W2   = (const float*)d_in[4];
    const float* W3   = (const float*)d_in[5];
    const float* W4   = (const float*)d_in[6];
    const float* bn   = (const float*)d_in[7];
    const int* nbr1   = (const int*)d_in[8];
    const int* nbrt   = (const int*)d_in[9];
    const int* nbr2   = (const int*)d_in[10];
    const int* nbr3   = (const int*)d_in[11];
    const int* nbr4   = (const int*)d_in[12];

    uint8_t* ws = (uint8_t*)d_ws;
    size_t off = 0;
    auto carve = [&](size_t bytes) -> void* {
        void* p = ws + off;
        off += (bytes + 255) & ~(size_t)255;
        return p;
    };
    uint16_t* xb  = (uint16_t*)carve((size_t)N * 128 * 2);
    uint16_t* hA  = (uint16_t*)carve((size_t)N * 64 * 2);
    uint16_t* hB  = (uint16_t*)carve((size_t)N * 64 * 2);
    uint16_t* p1  = (uint16_t*)carve((size_t)27 * 128 * 64 * 2);
    uint16_t* pt  = (uint16_t*)carve((size_t)27 * 64 * 64 * 2);
    uint16_t* p2  = (uint16_t*)carve((size_t)9 * 64 * 64 * 2);
    uint16_t* p3  = (uint16_t*)carve((size_t)9 * 64 * 64 * 2);
    uint16_t* p4  = (uint16_t*)carve((size_t)27 * 64 * 64 * 2);
    float*    bnp = (float*)carve((size_t)4 * 2 * 64 * 4);

    // prologue: convert + pack (re-done every call; ws is re-poisoned)
    const int n8 = N * 16;  // N*128/8
    convert_x<<<(n8 + 255) / 256, 256, 0, stream>>>(x, xb, n8);
    pack_weights<<<dim3(108, 6), 256, 0, stream>>>(W1, Wt, W2, W3, W4, bn,
                                                   p1, pt, p2, p3, p4, bnp);

    const int grid = (N + 31) / 32;   // 32 rows per 2-wave workgroup
    conv_layer<128, 27, 0><<<grid, 128, 0, stream>>>(xb, p1, nbr1, N, bnp + 0,   nullptr, hA, nullptr);
    conv_layer<64,  27, 1><<<grid, 128, 0, stream>>>(hA, pt, nbrt, N, nullptr,   skip,    hB, nullptr);
    conv_layer<64,   9, 0><<<grid, 128, 0, stream>>>(hB, p2, nbr2, N, bnp + 128, nullptr, hA, nullptr);
    conv_layer<64,   9, 0><<<grid, 128, 0, stream>>>(hA, p3, nbr3, N, bnp + 256, nullptr, hB, nullptr);
    conv_layer<64,  27, 2><<<grid, 128, 0, stream>>>(hB, p4, nbr4, N, bnp + 384, nullptr, nullptr, (float*)d_out);
}